// Round 9
// baseline (1163.819 us; speedup 1.0000x reference)
//
#include <hip/hip_runtime.h>
#include <hip/hip_cooperative_groups.h>
#include <math.h>

namespace cg = cooperative_groups;

// GCN fully fused: ONE cooperative kernel, grid.sync() between phases.
// Phases: h1 hist -> colscan -> binscan -> scatter1 -> sort2(+wt) -> 3x{gemm, agg} -> pool
// N=50000, E=800000, D=128, G=64. Requires N,src,dst < 65536, EB <= 512.

#define NDIM 128
#define LN_EPS 1e-5f
#define NGRAPH 64
#define EPB 2048

typedef __attribute__((ext_vector_type(8))) short short8;
typedef __attribute__((ext_vector_type(4))) float f32x4;

__device__ __forceinline__ ushort f2bf(float f) {
    unsigned u = __float_as_uint(f);
    return (ushort)((u + 0x7FFF + ((u >> 16) & 1)) >> 16);
}
__device__ __forceinline__ float bf2f(ushort b) {
    return __uint_as_float(((unsigned)b) << 16);
}

__device__ __forceinline__ uint block_excl_scan(uint v, uint* s) {
    int t = threadIdx.x;
    s[t] = v; __syncthreads();
    #pragma unroll
    for (int off = 1; off < 256; off <<= 1) {
        uint x = (t >= off) ? s[t - off] : 0u;
        __syncthreads();
        s[t] += x;
        __syncthreads();
    }
    uint incl = s[t];
    __syncthreads();
    return incl - v;
}

__global__ __launch_bounds__(256, 4) void kmega(
    const float* __restrict__ x, const int* __restrict__ ei, const int* __restrict__ batch,
    const float* __restrict__ Ws, const float* __restrict__ bs, const float* __restrict__ gammas,
    const float* __restrict__ betas, float* __restrict__ out, char* __restrict__ ws,
    int N, int E)
{
    cg::grid_group grid = cg::this_grid();
    __shared__ __align__(16) char smem[32768];

    const int* src = ei;
    const int* dst = ei + E;
    const int EB = (E + EPB - 1) / EPB;
    const int NB = (N + 255) >> 8;
    const int tid = threadIdx.x;
    const int G = gridDim.x;

    // workspace layout (256B aligned slots)
    size_t off = 0;
    auto take = [&](size_t bytes) { char* p = ws + off; off += (bytes + 255) & ~(size_t)255; return p; };
    int*    deg    = (int*)take((size_t)N * 4);
    int*    basep  = (int*)take((size_t)N * 4);
    float*  dinv   = (float*)take((size_t)N * 4);
    uint*   hist   = (uint*)take((size_t)EB * 256 * 4);
    uint*   colsum = (uint*)take(256 * 4);
    uint*   eoff   = (uint*)take(257 * 4);
    uint*   cbase  = (uint*)take(256 * 4);
    uint*   ebuf   = (uint*)take((size_t)E * 4);
    ushort* csr    = (ushort*)take(((size_t)E + 256u * 772u) * 2);
    int*    gse    = (int*)take(2 * NGRAPH * 4);
    ushort* Wt     = (ushort*)take((size_t)3 * NDIM * NDIM * 2);
    ushort* bufA   = (ushort*)take((size_t)N * NDIM * 2);
    ushort* bufB   = (ushort*)take((size_t)N * NDIM * 2);
    int* gstart = gse;
    int* gend   = gse + NGRAPH;

    // ---- P0: level-1 histogram (hist[b][j] = #edges in chunk b with dst>>8==j)
    {
        uint* sh = (uint*)smem;
        for (int b = blockIdx.x; b < EB; b += G) {
            sh[tid] = 0; __syncthreads();
            int e0 = b * EPB;
            #pragma unroll
            for (int i = 0; i < 8; i++) {
                int e = e0 + i * 256 + tid;
                if (e < E) atomicAdd(&sh[((uint)dst[e]) >> 8], 1u);
            }
            __syncthreads();
            hist[(size_t)b * 256 + tid] = sh[tid];     // own slot only -> no extra barrier
        }
    }
    grid.sync();

    // ---- P1: per-bin column scan
    for (int j = blockIdx.x; j < 256; j += G) {
        uint v0 = (2 * tid     < EB) ? hist[(size_t)(2 * tid) * 256 + j] : 0u;
        uint v1 = (2 * tid + 1 < EB) ? hist[(size_t)(2 * tid + 1) * 256 + j] : 0u;
        uint pair = v0 + v1;
        uint excl = block_excl_scan(pair, (uint*)smem);
        if (2 * tid < EB)     hist[(size_t)(2 * tid) * 256 + j] = excl;
        if (2 * tid + 1 < EB) hist[(size_t)(2 * tid + 1) * 256 + j] = excl + v0;
        if (tid == 255) colsum[j] = excl + pair;
        __syncthreads();
    }
    grid.sync();

    // ---- P2: bin scan (block 0 only)
    if (blockIdx.x == 0) {
        uint total = colsum[tid];
        uint er = block_excl_scan(total, (uint*)smem);
        eoff[tid] = er;
        if (tid == 255) eoff[256] = er + total;
        uint ep = block_excl_scan((total + 3u) & ~3u, (uint*)smem);
        cbase[tid] = ep + 768u * (uint)tid;
    }
    grid.sync();

    // ---- P3: scatter edges into dst>>8 buckets, packed (dst<<16)|src
    {
        uint* soff = (uint*)smem;
        uint* scur = (uint*)smem + 256;
        for (int b = blockIdx.x; b < EB; b += G) {
            soff[tid] = eoff[tid] + hist[(size_t)b * 256 + tid];
            scur[tid] = 0;
            __syncthreads();
            int e0 = b * EPB;
            #pragma unroll
            for (int i = 0; i < 8; i++) {
                int e = e0 + i * 256 + tid;
                if (e < E) {
                    uint d = (uint)dst[e], sv = (uint)src[e];
                    uint bin = d >> 8;
                    uint r = atomicAdd(&scur[bin], 1u);
                    ebuf[soff[bin] + r] = (d << 16) | sv;
                }
            }
            __syncthreads();
        }
    }
    grid.sync();

    // ---- P4: per-bucket sort -> csr/deg/base/dinv/gse; spare blocks convert weights
    if (blockIdx.x < NB) {
        int b = blockIdx.x;
        uint* h  = (uint*)smem;
        uint* nb = h + 256;
        uint* s  = h + 512;
        uint lo = eoff[b];
        int cnt = (int)(eoff[b + 1] - lo);
        h[tid] = 0; __syncthreads();
        for (int i = tid; i < cnt; i += 256)
            atomicAdd(&h[(ebuf[lo + i] >> 16) & 255u], 1u);
        __syncthreads();
        uint dg = h[tid];
        uint excl = block_excl_scan((dg + 3u) & ~3u, s);
        uint myb = cbase[b] + excl;
        nb[tid] = myb;
        int n = b * 256 + tid;
        if (n < N) {
            basep[n] = (int)myb;
            deg[n] = (int)dg;
            dinv[n] = rsqrtf((float)(dg + 1u));
            int g = batch[n];
            if (n == 0 || batch[n - 1] != g) gstart[g] = n;
            if (n == N - 1 || batch[n + 1] != g) gend[g] = n + 1;
        }
        h[tid] = 0; __syncthreads();
        for (int i = tid; i < cnt; i += 256) {
            uint e = ebuf[lo + i];
            uint bin = (e >> 16) & 255u;
            uint r = atomicAdd(&h[bin], 1u);
            csr[nb[bin] + r] = (ushort)(e & 0xFFFFu);
        }
    } else if (blockIdx.x < NB + 3) {
        int l = blockIdx.x - NB;
        const float* wsrc = Ws + (size_t)l * NDIM * NDIM;
        char* o = (char*)(Wt + (size_t)l * NDIM * NDIM);
        for (int idx = tid; idx < NDIM * NDIM; idx += 256) {
            int k = idx >> 7, nn = idx & 127;
            int byte = ((nn * NDIM + k) * 2) ^ ((nn & 7) << 4);
            *(ushort*)(o + byte) = f2bf(wsrc[idx]);
        }
    }
    grid.sync();

    // ---- 3 layers: gemm -> sync -> agg -> sync
    const int wave = tid >> 6, lane = tid & 63;
    const int l15 = lane & 15, lhi = lane >> 4;
    for (int l = 0; l < 3; l++) {
        // gemm: C=(A@W)*dinv, bf16 MFMA, BM=64, Wt staged in LDS (pre-swizzled)
        {
            const float4* g4 = (const float4*)(Wt + (size_t)l * NDIM * NDIM);
            float4* s4 = (float4*)smem;
            #pragma unroll
            for (int i = 0; i < 8; i++) s4[tid + 256 * i] = g4[tid + 256 * i];
            __syncthreads();

            bool af32 = (l == 0);
            int ntile = (N + 63) >> 6;
            for (int tile = blockIdx.x; tile < ntile; tile += G) {
                int rw = tile * 64 + wave * 16;
                f32x4 acc[8];
                #pragma unroll
                for (int n = 0; n < 8; n++) acc[n] = f32x4{0.f, 0.f, 0.f, 0.f};
                #pragma unroll
                for (int ks = 0; ks < 4; ks++) {
                    int k = ks * 32 + lhi * 8;
                    short8 a = short8{};
                    int r = rw + l15;
                    if (r < N) {
                        if (af32) {
                            float4 v0 = *(const float4*)&x[(size_t)r * NDIM + k];
                            float4 v1 = *(const float4*)&x[(size_t)r * NDIM + k + 4];
                            short8 t;
                            t[0] = (short)f2bf(v0.x); t[1] = (short)f2bf(v0.y);
                            t[2] = (short)f2bf(v0.z); t[3] = (short)f2bf(v0.w);
                            t[4] = (short)f2bf(v1.x); t[5] = (short)f2bf(v1.y);
                            t[6] = (short)f2bf(v1.z); t[7] = (short)f2bf(v1.w);
                            a = t;
                        } else {
                            a = *(const short8*)&bufA[(size_t)r * NDIM + k];
                        }
                    }
                    #pragma unroll
                    for (int n = 0; n < 8; n++) {
                        int nn = n * 16 + l15;
                        int byte = (nn * 256 + k * 2) ^ ((nn & 7) << 4);
                        short8 bfr = *(const short8*)(smem + byte);
                        acc[n] = __builtin_amdgcn_mfma_f32_16x16x32_bf16(a, bfr, acc[n], 0, 0, 0);
                    }
                }
                #pragma unroll
                for (int r = 0; r < 4; r++) {
                    int row = rw + lhi * 4 + r;
                    if (row < N) {
                        float dn = dinv[row];
                        #pragma unroll
                        for (int n = 0; n < 8; n++)
                            bufB[(size_t)row * NDIM + n * 16 + l15] = f2bf(acc[n][r] * dn);
                    }
                }
            }
        }
        grid.sync();

        // agg: half-wave per node, MLP-8 gather + bias + LN + ReLU
        {
            const float4* bias = (const float4*)(bs + l * NDIM);
            const float4* gam  = (const float4*)(gammas + l * NDIM);
            const float4* bet  = (const float4*)(betas + l * NDIM);
            const ushort4* hv = (const ushort4*)bufB;
            int l4 = tid & 31;
            int nchunk = (N + 7) >> 3;
            for (int c = blockIdx.x; c < nchunk; c += G) {
                int n = c * 8 + (tid >> 5);
                if (n < N) {
                    ushort4 sv = hv[(size_t)n * 32 + l4];
                    float a0 = bf2f(sv.x), a1 = bf2f(sv.y), a2 = bf2f(sv.z), a3 = bf2f(sv.w);
                    int b0 = basep[n], dg = deg[n];
                    int nfull = dg & ~7;
                    ushort4 sa, sb;
                    if (nfull > 0) {
                        sa = *(const ushort4*)&csr[b0];
                        sb = *(const ushort4*)&csr[b0 + 4];
                    }
                    for (int i = 0; i < nfull; i += 8) {
                        ushort4 ca = sa, cb = sb;
                        if (i + 8 < nfull) {
                            sa = *(const ushort4*)&csr[b0 + i + 8];
                            sb = *(const ushort4*)&csr[b0 + i + 12];
                        }
                        ushort4 t0 = hv[(size_t)ca.x * 32 + l4];
                        ushort4 t1 = hv[(size_t)ca.y * 32 + l4];
                        ushort4 t2 = hv[(size_t)ca.z * 32 + l4];
                        ushort4 t3 = hv[(size_t)ca.w * 32 + l4];
                        ushort4 t4 = hv[(size_t)cb.x * 32 + l4];
                        ushort4 t5 = hv[(size_t)cb.y * 32 + l4];
                        ushort4 t6 = hv[(size_t)cb.z * 32 + l4];
                        ushort4 t7 = hv[(size_t)cb.w * 32 + l4];
                        a0 += bf2f(t0.x) + bf2f(t1.x) + bf2f(t2.x) + bf2f(t3.x)
                            + bf2f(t4.x) + bf2f(t5.x) + bf2f(t6.x) + bf2f(t7.x);
                        a1 += bf2f(t0.y) + bf2f(t1.y) + bf2f(t2.y) + bf2f(t3.y)
                            + bf2f(t4.y) + bf2f(t5.y) + bf2f(t6.y) + bf2f(t7.y);
                        a2 += bf2f(t0.z) + bf2f(t1.z) + bf2f(t2.z) + bf2f(t3.z)
                            + bf2f(t4.z) + bf2f(t5.z) + bf2f(t6.z) + bf2f(t7.z);
                        a3 += bf2f(t0.w) + bf2f(t1.w) + bf2f(t2.w) + bf2f(t3.w)
                            + bf2f(t4.w) + bf2f(t5.w) + bf2f(t6.w) + bf2f(t7.w);
                    }
                    for (int i = nfull; i < dg; i++) {
                        int s = csr[b0 + i];
                        ushort4 t = hv[(size_t)s * 32 + l4];
                        a0 += bf2f(t.x); a1 += bf2f(t.y); a2 += bf2f(t.z); a3 += bf2f(t.w);
                    }
                    float dn = dinv[n];
                    a0 *= dn; a1 *= dn; a2 *= dn; a3 *= dn;
                    float4 bv = bias[l4];
                    a0 += bv.x; a1 += bv.y; a2 += bv.z; a3 += bv.w;
                    float s1 = a0 + a1 + a2 + a3;
                    float s2 = a0 * a0 + a1 * a1 + a2 * a2 + a3 * a3;
                    #pragma unroll
                    for (int o = 1; o < 32; o <<= 1) {
                        s1 += __shfl_xor(s1, o);
                        s2 += __shfl_xor(s2, o);
                    }
                    float mu = s1 * (1.f / NDIM);
                    float var = s2 * (1.f / NDIM) - mu * mu;
                    float rs = rsqrtf(var + LN_EPS);
                    float4 gv = gam[l4];
                    float4 be = bet[l4];
                    ushort4 y;
                    y.x = f2bf(fmaxf(gv.x * (a0 - mu) * rs + be.x, 0.f));
                    y.y = f2bf(fmaxf(gv.y * (a1 - mu) * rs + be.y, 0.f));
                    y.z = f2bf(fmaxf(gv.z * (a2 - mu) * rs + be.z, 0.f));
                    y.w = f2bf(fmaxf(gv.w * (a3 - mu) * rs + be.w, 0.f));
                    ((ushort4*)bufA)[(size_t)n * 32 + l4] = y;
                }
            }
        }
        grid.sync();
    }

    // ---- pool: one block per graph, no atomics, writes out fully (no memset needed)
    if (blockIdx.x < NGRAPH) {
        int g = blockIdx.x;
        int st = gstart[g], en = gend[g];
        int d = tid & 127, half = tid >> 7;
        float partial = 0.f;
        for (int r = st + half; r < en; r += 2)
            partial += bf2f(bufA[(size_t)r * NDIM + d]);
        float* ps = (float*)smem;
        ps[tid] = partial;
        __syncthreads();
        if (tid < 128) {
            float c = (float)(en - st);
            out[g * NDIM + tid] = (ps[tid] + ps[tid + 128]) / fmaxf(c, 1.f);
        }
    }
}

// ---------------- launch ----------------

extern "C" void kernel_launch(void* const* d_in, const int* in_sizes, int n_in,
                              void* d_out, int out_size, void* d_ws, size_t ws_size,
                              hipStream_t stream) {
    const float* x      = (const float*)d_in[0];
    const int*   ei     = (const int*)d_in[1];
    const int*   batch  = (const int*)d_in[2];
    const float* Ws     = (const float*)d_in[3];
    const float* bs     = (const float*)d_in[4];
    const float* gammas = (const float*)d_in[5];
    const float* betas  = (const float*)d_in[6];
    float* out = (float*)d_out;
    char* ws = (char*)d_ws;

    int N = in_sizes[0] / NDIM;
    int E = in_sizes[1] / 2;

    // co-residency-safe grid: occupancy * 256 CUs, clamped; all phases grid-stride
    int occ = 0;
    hipOccupancyMaxActiveBlocksPerMultiprocessor(&occ, kmega, 256, 0);
    int G = occ * 256;
    if (G > 1024) G = 1024;
    if (G < 256) G = 256;

    void* args[] = { (void*)&x, (void*)&ei, (void*)&batch, (void*)&Ws, (void*)&bs,
                     (void*)&gammas, (void*)&betas, (void*)&out, (void*)&ws,
                     (void*)&N, (void*)&E };
    hipLaunchCooperativeKernel((const void*)kmega, dim3(G), dim3(256), args, 0, stream);
}

// Round 10
// 271.070 us; speedup vs baseline: 4.2934x; 4.2934x over previous
//
#include <hip/hip_runtime.h>
#include <math.h>

// GCN: atomic-free bucket-sort CSR build, bf16-MFMA GEMM, fused gather+LN+ReLU agg,
// per-graph pool. 9 dispatches total (binscan/wt/div/memset folded).
// N=50000, E=800000, D=128, G=64. Requires N,src,dst < 65536, EB <= 512.

#define NDIM 128
#define LN_EPS 1e-5f
#define NGRAPH 64
#define EPB 2048

typedef __attribute__((ext_vector_type(8))) short short8;
typedef __attribute__((ext_vector_type(8))) ushort ushort8;
typedef __attribute__((ext_vector_type(4))) float f32x4;

__device__ __forceinline__ ushort f2bf(float f) {
    unsigned u = __float_as_uint(f);
    return (ushort)((u + 0x7FFF + ((u >> 16) & 1)) >> 16);
}
__device__ __forceinline__ float bf2f(ushort b) {
    return __uint_as_float(((unsigned)b) << 16);
}

__device__ __forceinline__ uint block_excl_scan(uint v, uint* s) {
    int t = threadIdx.x;
    s[t] = v; __syncthreads();
    #pragma unroll
    for (int off = 1; off < 256; off <<= 1) {
        uint x = (t >= off) ? s[t - off] : 0u;
        __syncthreads();
        s[t] += x;
        __syncthreads();
    }
    uint incl = s[t];
    __syncthreads();
    return incl - v;
}

// ---------------- graph build ----------------

__global__ __launch_bounds__(256) void k_h1(const int* __restrict__ dst, uint* __restrict__ hist, int E) {
    __shared__ uint h[256];
    int t = threadIdx.x, b = blockIdx.x;
    h[t] = 0; __syncthreads();
    int e0 = b * EPB;
    #pragma unroll
    for (int i = 0; i < 8; i++) {
        int e = e0 + i * 256 + t;
        if (e < E) atomicAdd(&h[((uint)dst[e]) >> 8], 1u);
    }
    __syncthreads();
    hist[(size_t)b * 256 + t] = h[t];
}

__global__ __launch_bounds__(256) void k_colscan(uint* __restrict__ hist, uint* __restrict__ colsum, int EB) {
    __shared__ uint s[256];
    int t = threadIdx.x, j = blockIdx.x;
    uint v0 = (2 * t     < EB) ? hist[(size_t)(2 * t) * 256 + j] : 0u;
    uint v1 = (2 * t + 1 < EB) ? hist[(size_t)(2 * t + 1) * 256 + j] : 0u;
    uint pair = v0 + v1;
    uint excl = block_excl_scan(pair, s);
    if (2 * t < EB)     hist[(size_t)(2 * t) * 256 + j] = excl;
    if (2 * t + 1 < EB) hist[(size_t)(2 * t + 1) * 256 + j] = excl + v0;
    if (t == 255) colsum[j] = excl + pair;
}

// scatter: per-block in-LDS scan of colsum replaces the old binscan kernel
__global__ __launch_bounds__(256) void k_scatter1(const int* __restrict__ src, const int* __restrict__ dst,
                                                  const uint* __restrict__ hist, const uint* __restrict__ colsum,
                                                  uint* __restrict__ ebuf, int E) {
    __shared__ uint s[256];
    __shared__ uint off[256];
    __shared__ uint cur[256];
    int t = threadIdx.x, b = blockIdx.x;
    uint er = block_excl_scan(colsum[t], s);          // eoff[t]
    off[t] = er + hist[(size_t)b * 256 + t];
    cur[t] = 0;
    __syncthreads();
    int e0 = b * EPB;
    #pragma unroll
    for (int i = 0; i < 8; i++) {
        int e = e0 + i * 256 + t;
        if (e < E) {
            uint d = (uint)dst[e], sv = (uint)src[e];
            uint bin = d >> 8;
            uint r = atomicAdd(&cur[bin], 1u);
            ebuf[off[bin] + r] = (d << 16) | sv;
        }
    }
}

// per-bucket sort -> csr/deg/base/dinv/gse; spare blocks (>=NB) convert weights
__global__ __launch_bounds__(256) void k_sort2(const uint* __restrict__ ebuf, const uint* __restrict__ colsum,
                                               const int* __restrict__ batch,
                                               ushort* __restrict__ csr, int* __restrict__ base,
                                               int* __restrict__ deg, float* __restrict__ dinv,
                                               int* __restrict__ gstart, int* __restrict__ gend,
                                               const float* __restrict__ Ws, ushort* __restrict__ Wt,
                                               int N, int NB) {
    __shared__ uint h[256], nb[256], s[256], er_arr[256], ep_arr[256];
    int t = threadIdx.x, b = blockIdx.x;
    if (b >= NB) {      // weight-prep rider blocks
        int l = b - NB;
        const float* wsrc = Ws + (size_t)l * NDIM * NDIM;
        char* o = (char*)(Wt + (size_t)l * NDIM * NDIM);
        for (int idx = t; idx < NDIM * NDIM; idx += 256) {
            int k = idx >> 7, nn = idx & 127;
            int byte = ((nn * NDIM + k) * 2) ^ ((nn & 7) << 4);
            *(ushort*)(o + byte) = f2bf(wsrc[idx]);
        }
        return;
    }
    uint total = colsum[t];
    uint er = block_excl_scan(total, s);
    er_arr[t] = er;
    uint ep = block_excl_scan((total + 3u) & ~3u, s);
    ep_arr[t] = ep;
    __syncthreads();
    uint lo = er_arr[b];
    int cnt = (int)colsum[b];
    uint cb = ep_arr[b] + 768u * (uint)b;
    h[t] = 0; __syncthreads();
    for (int i = t; i < cnt; i += 256)
        atomicAdd(&h[(ebuf[lo + i] >> 16) & 255u], 1u);
    __syncthreads();
    uint dg = h[t];
    uint excl = block_excl_scan((dg + 3u) & ~3u, s);
    uint myb = cb + excl;
    nb[t] = myb;
    int n = b * 256 + t;
    if (n < N) {
        base[n] = (int)myb;
        deg[n] = (int)dg;
        dinv[n] = rsqrtf((float)(dg + 1u));
        int g = batch[n];
        if (n == 0 || batch[n - 1] != g) gstart[g] = n;
        if (n == N - 1 || batch[n + 1] != g) gend[g] = n + 1;
    }
    h[t] = 0; __syncthreads();
    for (int i = t; i < cnt; i += 256) {
        uint e = ebuf[lo + i];
        uint bin = (e >> 16) & 255u;
        uint r = atomicAdd(&h[bin], 1u);
        csr[nb[bin] + r] = (ushort)(e & 0xFFFFu);
    }
}

// ---------------- GEMM: C[N,128] = (A @ W) * dinv[row], bf16 MFMA ----------------
// BM=64, 4 waves; epilogue repacks C-frags through LDS -> coalesced short8 stores.

template <bool AF32>
__global__ __launch_bounds__(256) void k_gemm(const void* __restrict__ Ap, const ushort* __restrict__ Wt,
                                              ushort* __restrict__ C, const float* __restrict__ dinv, int N) {
    __shared__ char sW[32768];
    __shared__ ushort sC[64 * NDIM];
    int tid = threadIdx.x;
    {
        const float4* g = (const float4*)Wt;
        float4* s = (float4*)sW;
        #pragma unroll
        for (int i = 0; i < 8; i++) s[tid + 256 * i] = g[tid + 256 * i];
    }
    __syncthreads();

    int wave = tid >> 6, lane = tid & 63;
    int l15 = lane & 15, lhi = lane >> 4;
    int rw = blockIdx.x * 64 + wave * 16;

    f32x4 acc[8];
    #pragma unroll
    for (int n = 0; n < 8; n++) acc[n] = f32x4{0.f, 0.f, 0.f, 0.f};

    const float*  Af = (const float*)Ap;
    const ushort* Ab = (const ushort*)Ap;

    #pragma unroll
    for (int ks = 0; ks < 4; ks++) {
        int k = ks * 32 + lhi * 8;
        short8 a = short8{};
        int r = rw + l15;
        if (r < N) {
            if (AF32) {
                float4 v0 = *(const float4*)&Af[(size_t)r * NDIM + k];
                float4 v1 = *(const float4*)&Af[(size_t)r * NDIM + k + 4];
                short8 t;
                t[0] = (short)f2bf(v0.x); t[1] = (short)f2bf(v0.y);
                t[2] = (short)f2bf(v0.z); t[3] = (short)f2bf(v0.w);
                t[4] = (short)f2bf(v1.x); t[5] = (short)f2bf(v1.y);
                t[6] = (short)f2bf(v1.z); t[7] = (short)f2bf(v1.w);
                a = t;
            } else {
                a = *(const short8*)&Ab[(size_t)r * NDIM + k];
            }
        }
        #pragma unroll
        for (int n = 0; n < 8; n++) {
            int nn = n * 16 + l15;
            int byte = (nn * 256 + k * 2) ^ ((nn & 7) << 4);
            short8 b = *(const short8*)(sW + byte);
            acc[n] = __builtin_amdgcn_mfma_f32_16x16x32_bf16(a, b, acc[n], 0, 0, 0);
        }
    }

    #pragma unroll
    for (int r = 0; r < 4; r++) {
        int row = rw + lhi * 4 + r;
        float dn = (row < N) ? dinv[row] : 0.f;
        #pragma unroll
        for (int n = 0; n < 8; n++)
            sC[(wave * 16 + lhi * 4 + r) * NDIM + n * 16 + l15] = f2bf(acc[n][r] * dn);
    }
    __syncthreads();
    int row0 = blockIdx.x * 64;
    #pragma unroll
    for (int i = 0; i < 4; i++) {
        int flat = tid + i * 256;
        int row = flat >> 4, c8 = (flat & 15) * 8;
        int gr = row0 + row;
        if (gr < N)
            *(short8*)&C[(size_t)gr * NDIM + c8] = *(const short8*)&sC[row * NDIM + c8];
    }
}

// ---------------- fused aggregate + bias + LN + ReLU (bf16), half-wave/node, MLP-8 ----------------

__global__ __launch_bounds__(256) void k_agg(const ushort* __restrict__ hw, ushort* __restrict__ out,
                                             const float* __restrict__ dinv, const int* __restrict__ base,
                                             const int* __restrict__ deg, const ushort* __restrict__ csr,
                                             const float* __restrict__ bias, const float* __restrict__ gamma,
                                             const float* __restrict__ beta, int N) {
    int gtid = blockIdx.x * 256 + threadIdx.x;
    int n = gtid >> 5;
    int l4 = threadIdx.x & 31;
    if (n >= N) return;

    const ushort4* hv = (const ushort4*)hw;
    ushort4 sv = hv[(size_t)n * 32 + l4];
    float a0 = bf2f(sv.x), a1 = bf2f(sv.y), a2 = bf2f(sv.z), a3 = bf2f(sv.w);

    int b0 = base[n], dg = deg[n];
    int nfull = dg & ~7;
    ushort4 sa, sb;
    if (nfull > 0) {
        sa = *(const ushort4*)&csr[b0];
        sb = *(const ushort4*)&csr[b0 + 4];
    }
    for (int i = 0; i < nfull; i += 8) {
        ushort4 ca = sa, cb = sb;
        if (i + 8 < nfull) {
            sa = *(const ushort4*)&csr[b0 + i + 8];
            sb = *(const ushort4*)&csr[b0 + i + 12];
        }
        ushort4 t0 = hv[(size_t)ca.x * 32 + l4];
        ushort4 t1 = hv[(size_t)ca.y * 32 + l4];
        ushort4 t2 = hv[(size_t)ca.z * 32 + l4];
        ushort4 t3 = hv[(size_t)ca.w * 32 + l4];
        ushort4 t4 = hv[(size_t)cb.x * 32 + l4];
        ushort4 t5 = hv[(size_t)cb.y * 32 + l4];
        ushort4 t6 = hv[(size_t)cb.z * 32 + l4];
        ushort4 t7 = hv[(size_t)cb.w * 32 + l4];
        a0 += bf2f(t0.x) + bf2f(t1.x) + bf2f(t2.x) + bf2f(t3.x)
            + bf2f(t4.x) + bf2f(t5.x) + bf2f(t6.x) + bf2f(t7.x);
        a1 += bf2f(t0.y) + bf2f(t1.y) + bf2f(t2.y) + bf2f(t3.y)
            + bf2f(t4.y) + bf2f(t5.y) + bf2f(t6.y) + bf2f(t7.y);
        a2 += bf2f(t0.z) + bf2f(t1.z) + bf2f(t2.z) + bf2f(t3.z)
            + bf2f(t4.z) + bf2f(t5.z) + bf2f(t6.z) + bf2f(t7.z);
        a3 += bf2f(t0.w) + bf2f(t1.w) + bf2f(t2.w) + bf2f(t3.w)
            + bf2f(t4.w) + bf2f(t5.w) + bf2f(t6.w) + bf2f(t7.w);
    }
    for (int i = nfull; i < dg; i++) {
        int s = csr[b0 + i];
        ushort4 t = hv[(size_t)s * 32 + l4];
        a0 += bf2f(t.x); a1 += bf2f(t.y); a2 += bf2f(t.z); a3 += bf2f(t.w);
    }

    float dn = dinv[n];
    a0 *= dn; a1 *= dn; a2 *= dn; a3 *= dn;

    float4 bv = ((const float4*)bias)[l4];
    a0 += bv.x; a1 += bv.y; a2 += bv.z; a3 += bv.w;

    float s1 = a0 + a1 + a2 + a3;
    float s2 = a0 * a0 + a1 * a1 + a2 * a2 + a3 * a3;
    #pragma unroll
    for (int o = 1; o < 32; o <<= 1) {
        s1 += __shfl_xor(s1, o);
        s2 += __shfl_xor(s2, o);
    }
    float mu = s1 * (1.f / NDIM);
    float var = s2 * (1.f / NDIM) - mu * mu;
    float rs = rsqrtf(var + LN_EPS);

    float4 gv = ((const float4*)gamma)[l4];
    float4 be = ((const float4*)beta)[l4];
    ushort4 y;
    y.x = f2bf(fmaxf(gv.x * (a0 - mu) * rs + be.x, 0.f));
    y.y = f2bf(fmaxf(gv.y * (a1 - mu) * rs + be.y, 0.f));
    y.z = f2bf(fmaxf(gv.z * (a2 - mu) * rs + be.z, 0.f));
    y.w = f2bf(fmaxf(gv.w * (a3 - mu) * rs + be.w, 0.f));
    ((ushort4*)out)[(size_t)n * 32 + l4] = y;
}

// ---------------- per-graph mean pool (no atomics, no memset, divide fused) ----------------
// 64 blocks; thread t = (row-slot t>>4, dim-chunk (t&15)*8); LDS tree reduce.

__global__ __launch_bounds__(256) void k_pool2(const ushort* __restrict__ h, const int* __restrict__ gstart,
                                               const int* __restrict__ gend, float* __restrict__ out) {
    __shared__ float ps[16][128];
    int t = threadIdx.x, g = blockIdx.x;
    int st = gstart[g], en = gend[g];
    int rslot = t >> 4, dc = (t & 15) * 8;
    float acc[8] = {0.f, 0.f, 0.f, 0.f, 0.f, 0.f, 0.f, 0.f};
    for (int r = st + rslot; r < en; r += 16) {
        ushort8 v = *(const ushort8*)&h[(size_t)r * NDIM + dc];
        #pragma unroll
        for (int j = 0; j < 8; j++) acc[j] += bf2f(v[j]);
    }
    #pragma unroll
    for (int j = 0; j < 8; j++) ps[rslot][dc + j] = acc[j];
    __syncthreads();
    if (t < 128) {
        float s = 0.f;
        #pragma unroll
        for (int k = 0; k < 16; k++) s += ps[k][t];
        float c = (float)(en - st);
        out[g * NDIM + t] = s / fmaxf(c, 1.f);
    }
}

// ---------------- launch (9 dispatches) ----------------

extern "C" void kernel_launch(void* const* d_in, const int* in_sizes, int n_in,
                              void* d_out, int out_size, void* d_ws, size_t ws_size,
                              hipStream_t stream) {
    const float* x      = (const float*)d_in[0];
    const int*   ei     = (const int*)d_in[1];
    const int*   batch  = (const int*)d_in[2];
    const float* Ws     = (const float*)d_in[3];
    const float* bs     = (const float*)d_in[4];
    const float* gammas = (const float*)d_in[5];
    const float* betas  = (const float*)d_in[6];
    float* out = (float*)d_out;

    int N = in_sizes[0] / NDIM;
    int E = in_sizes[1] / 2;
    const int* src = ei;
    const int* dst = ei + E;
    int EB = (E + EPB - 1) / EPB;
    int NB = (N + 255) / 256;

    char* w = (char*)d_ws;
    auto alloc = [&](size_t bytes) { char* p = w; w += (bytes + 255) & ~(size_t)255; return p; };
    int*    deg    = (int*)alloc((size_t)N * 4);
    int*    base   = (int*)alloc((size_t)N * 4);
    float*  dinv   = (float*)alloc((size_t)N * 4);
    uint*   hist   = (uint*)alloc((size_t)EB * 256 * 4);
    uint*   colsum = (uint*)alloc(256 * 4);
    uint*   ebuf   = (uint*)alloc((size_t)E * 4);
    ushort* csr    = (ushort*)alloc(((size_t)E + 256u * 772u) * 2);
    int*    gse    = (int*)alloc(2 * NGRAPH * 4);
    int*    gstart = gse;
    int*    gend   = gse + NGRAPH;
    ushort* Wt     = (ushort*)alloc((size_t)3 * NDIM * NDIM * 2);
    ushort* bufA   = (ushort*)alloc((size_t)N * NDIM * 2);
    ushort* bufB   = (ushort*)alloc((size_t)N * NDIM * 2);

    k_h1<<<EB, 256, 0, stream>>>(dst, hist, E);
    k_colscan<<<256, 256, 0, stream>>>(hist, colsum, EB);
    k_scatter1<<<EB, 256, 0, stream>>>(src, dst, hist, colsum, ebuf, E);
    k_sort2<<<NB + 3, 256, 0, stream>>>(ebuf, colsum, batch, csr, base, deg, dinv,
                                        gstart, gend, Ws, Wt, N, NB);

    int gGemm = (N + 63) / 64;
    int gAgg  = (N * 32 + 255) / 256;
    for (int l = 0; l < 3; l++) {
        const ushort* wl = Wt + (size_t)l * NDIM * NDIM;
        if (l == 0)
            k_gemm<true><<<gGemm, 256, 0, stream>>>((const void*)x, wl, bufB, dinv, N);
        else
            k_gemm<false><<<gGemm, 256, 0, stream>>>((const void*)bufA, wl, bufB, dinv, N);
        k_agg<<<gAgg, 256, 0, stream>>>(bufB, bufA, dinv, base, deg, csr,
                                        bs + l * NDIM, gammas + l * NDIM, betas + l * NDIM, N);
    }

    k_pool2<<<NGRAPH, 256, 0, stream>>>(bufA, gstart, gend, out);
}